// Round 7
// baseline (540.812 us; speedup 1.0000x reference)
//
#include <hip/hip_runtime.h>

// PhaMPN v7: transform-then-gather restructure.
//   binput = fedges @ W_i (MFMA, bf16); msg = bf16(sigmoid(binput))
//   5x: T = msg @ W_h               [k_mmul: pure streaming MFMA GEMM]
//       msg = bf16(sigmoid(binput + sum_8 T[egraph]))   [k_gscatter_sig]
//   (uses (sum msg[eg]) @ W == sum (msg @ W)[eg], W linear)
//   F = features @ Wo_top + b_o  (once);  U = msg5 @ Wo_bot
//   hidden = bf16(sigmoid(F + sum_8 U[agraph]));  out = segment-mean(hidden)

typedef __attribute__((ext_vector_type(4))) float f32x4;
typedef __attribute__((ext_vector_type(8))) short s16x8;
typedef unsigned short u16;

constexpr int Nn   = 50000;
constexpr int Ee   = 150000;
constexpr int NBn  = 8;
constexpr int Hh   = 128;
constexpr int FFn  = 40;
constexpr int Bm   = 500;
constexpr int ITERS = 5;       // DEPTH - 1
constexpr int KI   = 72;       // fedges/features tile stride (K padded -> 64)
constexpr int ACCW = 132;      // f32 acc stride (k_binput / k_fgemm)
constexpr int ACC2 = 130;      // f32 acc stride (k_mmul)

__device__ __forceinline__ float sigmoidf_(float x) {
    return 1.0f / (1.0f + __expf(-x));
}
// f32 -> bf16 round-to-nearest-even (finite values only)
__device__ __forceinline__ u16 f2bf(float f) {
    unsigned u = __float_as_uint(f);
    u += 0x7fffu + ((u >> 16) & 1u);
    return (u16)(u >> 16);
}
__device__ __forceinline__ float bflo(unsigned u) { return __uint_as_float(u << 16); }
__device__ __forceinline__ float bfhi(unsigned u) { return __uint_as_float(u & 0xffff0000u); }
__device__ __forceinline__ float bf1(u16 h) { return __uint_as_float(((unsigned)h) << 16); }
__device__ __forceinline__ unsigned pack2(float x, float y) {
    return (unsigned)f2bf(x) | ((unsigned)f2bf(y) << 16);
}
__device__ __forceinline__ void add8(float* a, uint4 v) {
    a[0] += bflo(v.x); a[1] += bfhi(v.x); a[2] += bflo(v.y); a[3] += bfhi(v.y);
    a[4] += bflo(v.z); a[5] += bfhi(v.z); a[6] += bflo(v.w); a[7] += bfhi(v.w);
}
__device__ __forceinline__ void set8(float* a, uint4 v) {
    a[0] = bflo(v.x); a[1] = bfhi(v.x); a[2] = bflo(v.y); a[3] = bfhi(v.y);
    a[4] = bflo(v.z); a[5] = bfhi(v.z); a[6] = bflo(v.w); a[7] = bfhi(v.w);
}

// ---------------------------------------------------------------------------
// Fragment-major weights: flat i -> f=i>>9, l=(i>>3)&63, e=i&7; ks=f>>3, c=f&7;
// k = ks*32 + (l>>4)*8 + e; n = c*16 + (l&15).
// MFMA B-read: ((s16x8*)W)[f*64 + lane]  (lane-linear, conflict-free).
// ---------------------------------------------------------------------------
__global__ __launch_bounds__(256) void k_prep1(
    const float* __restrict__ W_h, const float* __restrict__ W_i,
    u16* __restrict__ wt_h, u16* __restrict__ wt_i)
{
    int i = blockIdx.x * 256 + threadIdx.x;
    if (i < Hh * Hh) {                       // wt_h: 32 frags
        int f = i >> 9, l = (i >> 3) & 63, e = i & 7;
        int ks = f >> 3, c = f & 7;
        int k = ks * 32 + (l >> 4) * 8 + e, n = c * 16 + (l & 15);
        wt_h[i] = f2bf(W_h[k * Hh + n]);
    } else {
        int j = i - Hh * Hh;
        if (j < 16 * 512) {                  // wt_i: 16 frags, k<41 else 0
            int f = j >> 9, l = (j >> 3) & 63, e = j & 7;
            int ks = f >> 3, c = f & 7;
            int k = ks * 32 + (l >> 4) * 8 + e, n = c * 16 + (l & 15);
            wt_i[j] = (k < 41) ? f2bf(W_i[k * Hh + n]) : (u16)0;
        }
    }
}

// wt_ot: rows 0..39 of W_o (K padded to 64); wt_ob: rows 40..167 of W_o (K=128)
__global__ __launch_bounds__(256) void k_prep_o(
    const float* __restrict__ W_o, u16* __restrict__ wt_ot, u16* __restrict__ wt_ob)
{
    int i = blockIdx.x * 256 + threadIdx.x;
    if (i < 16 * 512) {
        int f = i >> 9, l = (i >> 3) & 63, e = i & 7;
        int ks = f >> 3, c = f & 7;
        int k = ks * 32 + (l >> 4) * 8 + e, n = c * 16 + (l & 15);
        wt_ot[i] = (k < FFn) ? f2bf(W_o[k * Hh + n]) : (u16)0;
    } else {
        int j = i - 16 * 512;
        if (j < 32 * 512) {
            int f = j >> 9, l = (j >> 3) & 63, e = j & 7;
            int ks = f >> 3, c = f & 7;
            int k = ks * 32 + (l >> 4) * 8 + e, n = c * 16 + (l & 15);
            wt_ob[j] = f2bf(W_o[(FFn + k) * Hh + n]);
        }
    }
}

// ---------------------------------------------------------------------------
// Kernel 1 (MFMA, 512 thr): binput_bf = bf16(fedges @ W_i); msg = bf16(sigmoid)
// 128 rows / block, 8 waves, K=64 (padded).
// ---------------------------------------------------------------------------
union BinSmem {
    struct { u16 Wi[16 * 512]; u16 A[Hh * KI]; } s;  // 16384 + 18432 B
    float acc[Hh][ACCW];                             // 67584 B
};

__global__ __launch_bounds__(512, 4) void k_binput(
    const float* __restrict__ fedges, const u16* __restrict__ wt_i,
    u16* __restrict__ binput_bf, u16* __restrict__ msg)
{
    __shared__ BinSmem u;
    const int t = threadIdx.x;
    const int row0 = blockIdx.x * 128;
    const int nvalid = min(128, Ee - row0);

    {
        uint4 z = make_uint4(0, 0, 0, 0);
        for (int i = t; i < Hh * KI / 8; i += 512) {
            if (i < 1024) ((uint4*)u.s.Wi)[i] = ((const uint4*)wt_i)[i];
            ((uint4*)u.s.A)[i] = z;
        }
    }
    __syncthreads();
    for (int i = t; i < nvalid * 41; i += 512) {
        int r = i / 41, k = i - r * 41;
        u.s.A[r * KI + k] = f2bf(fedges[(size_t)row0 * 41 + i]);
    }
    __syncthreads();

    const int lane = t & 63, wid = t >> 6, l15 = lane & 15, l4 = lane >> 4;
    f32x4 acc[8];
    #pragma unroll
    for (int b = 0; b < 8; ++b) acc[b] = (f32x4){0.f, 0.f, 0.f, 0.f};

    #pragma unroll
    for (int ks = 0; ks < 2; ++ks) {
        s16x8 a = *(const s16x8*)&u.s.A[(wid * 16 + l15) * KI + ks * 32 + l4 * 8];
        #pragma unroll
        for (int c = 0; c < 8; ++c) {
            s16x8 b = ((const s16x8*)u.s.Wi)[(ks * 8 + c) * 64 + lane];
            acc[c] = __builtin_amdgcn_mfma_f32_16x16x32_bf16(a, b, acc[c], 0, 0, 0);
        }
    }
    __syncthreads();

    #pragma unroll
    for (int c = 0; c < 8; ++c)
        #pragma unroll
        for (int j = 0; j < 4; ++j)
            u.acc[wid * 16 + l4 * 4 + j][c * 16 + l15] = acc[c][j];
    __syncthreads();

    for (int i = t; i < Hh * 16; i += 512) {
        int row = i >> 4, seg = i & 15, grow = row0 + row;
        if (grow < Ee) {
            float4 a0 = *(const float4*)&u.acc[row][seg * 8];
            float4 a1 = *(const float4*)&u.acc[row][seg * 8 + 4];
            size_t o = (size_t)grow * Hh + seg * 8;
            uint4 bv;
            bv.x = pack2(a0.x, a0.y); bv.y = pack2(a0.z, a0.w);
            bv.z = pack2(a1.x, a1.y); bv.w = pack2(a1.z, a1.w);
            *(uint4*)&binput_bf[o] = bv;
            uint4 m;
            m.x = pack2(sigmoidf_(a0.x), sigmoidf_(a0.y));
            m.y = pack2(sigmoidf_(a0.z), sigmoidf_(a0.w));
            m.z = pack2(sigmoidf_(a1.x), sigmoidf_(a1.y));
            m.w = pack2(sigmoidf_(a1.z), sigmoidf_(a1.w));
            *(uint4*)&msg[o] = m;
        }
    }
}

// ---------------------------------------------------------------------------
// k_mmul (MFMA, 256 thr): dst = bf16(src @ Wfrag), K=128, nrows rows.
// 64 rows / block, 4 waves. Pure streaming GEMM; A-frags direct from global.
// LDS: union(Wfrag 32KB | acc 33.3KB) -> 4 blocks/CU.
// ---------------------------------------------------------------------------
__global__ __launch_bounds__(256, 4) void k_mmul(
    const u16* __restrict__ src, const u16* __restrict__ wfrag,
    u16* __restrict__ dst, int nrows)
{
    __shared__ union { u16 W[Hh * Hh]; float acc[64][ACC2]; } u;
    const int t = threadIdx.x;
    const int row0 = blockIdx.x * 64;
    const int lane = t & 63, wid = t >> 6, l15 = lane & 15, l4 = lane >> 4;

    for (int i = t; i < Hh * Hh / 8; i += 256)
        ((uint4*)u.W)[i] = ((const uint4*)wfrag)[i];

    const int arow = row0 + wid * 16 + l15;
    s16x8 afrag[4];
    if (arow < nrows) {
        #pragma unroll
        for (int ks = 0; ks < 4; ++ks)
            afrag[ks] = *(const s16x8*)(src + (size_t)arow * Hh + ks * 32 + l4 * 8);
    } else {
        #pragma unroll
        for (int ks = 0; ks < 4; ++ks)
            afrag[ks] = (s16x8){0, 0, 0, 0, 0, 0, 0, 0};
    }
    __syncthreads();

    f32x4 acc[8];
    #pragma unroll
    for (int b = 0; b < 8; ++b) acc[b] = (f32x4){0.f, 0.f, 0.f, 0.f};
    #pragma unroll
    for (int ks = 0; ks < 4; ++ks)
        #pragma unroll
        for (int c = 0; c < 8; ++c) {
            s16x8 b = ((const s16x8*)u.W)[(ks * 8 + c) * 64 + lane];
            acc[c] = __builtin_amdgcn_mfma_f32_16x16x32_bf16(afrag[ks], b, acc[c], 0, 0, 0);
        }
    __syncthreads();   // W dead

    #pragma unroll
    for (int c = 0; c < 8; ++c)
        #pragma unroll
        for (int j = 0; j < 4; ++j)
            u.acc[wid * 16 + l4 * 4 + j][c * 16 + l15] = acc[c][j];
    __syncthreads();

    for (int i = t; i < 64 * 16; i += 256) {
        int r = i >> 4, seg = i & 15, g = row0 + r;
        if (g < nrows) {
            float4 a0 = *(const float4*)&u.acc[r][seg * 8];
            float4 a1 = *(const float4*)&u.acc[r][seg * 8 + 4];
            uint4 m;
            m.x = pack2(a0.x, a0.y); m.y = pack2(a0.z, a0.w);
            m.z = pack2(a1.x, a1.y); m.w = pack2(a1.z, a1.w);
            *(uint4*)&dst[(size_t)g * Hh + seg * 8] = m;
        }
    }
}

// ---------------------------------------------------------------------------
// k_gscatter_sig: out[row] = bf16(sigmoid(base[row] + sum_8 T[graph[row][j]]))
// 8 lanes/row x 32B; all 16 gather loads in flight; no LDS, no barriers.
// ---------------------------------------------------------------------------
__global__ __launch_bounds__(256, 4) void k_gscatter_sig(
    const u16* __restrict__ T, const int* __restrict__ graph,
    const u16* __restrict__ base, u16* __restrict__ out, int nrows)
{
    const int gid = blockIdx.x * 256 + threadIdx.x;
    const int row = gid >> 3;
    const int s   = gid & 7;
    if (row >= nrows) return;

    const int4 q0 = ((const int4*)graph)[row * 2];
    const int4 q1 = ((const int4*)graph)[row * 2 + 1];
    const u16* bp = T + (size_t)s * 16;

    const u16* p0 = bp + (size_t)q0.x * Hh;
    const u16* p1 = bp + (size_t)q0.y * Hh;
    const u16* p2 = bp + (size_t)q0.z * Hh;
    const u16* p3 = bp + (size_t)q0.w * Hh;
    const u16* p4 = bp + (size_t)q1.x * Hh;
    const u16* p5 = bp + (size_t)q1.y * Hh;
    const u16* p6 = bp + (size_t)q1.z * Hh;
    const u16* p7 = bp + (size_t)q1.w * Hh;

    uint4 v0a = *(const uint4*)p0, v0b = *(const uint4*)(p0 + 8);
    uint4 v1a = *(const uint4*)p1, v1b = *(const uint4*)(p1 + 8);
    uint4 v2a = *(const uint4*)p2, v2b = *(const uint4*)(p2 + 8);
    uint4 v3a = *(const uint4*)p3, v3b = *(const uint4*)(p3 + 8);
    uint4 v4a = *(const uint4*)p4, v4b = *(const uint4*)(p4 + 8);
    uint4 v5a = *(const uint4*)p5, v5b = *(const uint4*)(p5 + 8);
    uint4 v6a = *(const uint4*)p6, v6b = *(const uint4*)(p6 + 8);
    uint4 v7a = *(const uint4*)p7, v7b = *(const uint4*)(p7 + 8);

    const u16* bs = base + (size_t)row * Hh + (size_t)s * 16;
    uint4 b0 = *(const uint4*)bs, b1 = *(const uint4*)(bs + 8);

    float a[16];
    set8(a, b0); set8(a + 8, b1);
    add8(a, v0a); add8(a + 8, v0b);
    add8(a, v1a); add8(a + 8, v1b);
    add8(a, v2a); add8(a + 8, v2b);
    add8(a, v3a); add8(a + 8, v3b);
    add8(a, v4a); add8(a + 8, v4b);
    add8(a, v5a); add8(a + 8, v5b);
    add8(a, v6a); add8(a + 8, v6b);
    add8(a, v7a); add8(a + 8, v7b);

    uint4 o0, o1;
    o0.x = pack2(sigmoidf_(a[0]),  sigmoidf_(a[1]));
    o0.y = pack2(sigmoidf_(a[2]),  sigmoidf_(a[3]));
    o0.z = pack2(sigmoidf_(a[4]),  sigmoidf_(a[5]));
    o0.w = pack2(sigmoidf_(a[6]),  sigmoidf_(a[7]));
    o1.x = pack2(sigmoidf_(a[8]),  sigmoidf_(a[9]));
    o1.y = pack2(sigmoidf_(a[10]), sigmoidf_(a[11]));
    o1.z = pack2(sigmoidf_(a[12]), sigmoidf_(a[13]));
    o1.w = pack2(sigmoidf_(a[14]), sigmoidf_(a[15]));
    u16* q = out + (size_t)row * Hh + (size_t)s * 16;
    *(uint4*)q       = o0;
    *(uint4*)(q + 8) = o1;
}

// ---------------------------------------------------------------------------
// k_fgemm (MFMA, 256 thr): F = bf16(features @ Wo_top + b_o), K=64 (padded 40)
// 64 rows / block, 4 waves. No sigmoid (applied later with the gather).
// ---------------------------------------------------------------------------
union FSmem {
    struct { u16 Wi[16 * 512]; u16 A[64 * KI]; } s;  // 16384 + 9216 B
    float acc[64][ACCW];                             // 33792 B
};

__global__ __launch_bounds__(256, 4) void k_fgemm(
    const float* __restrict__ features, const u16* __restrict__ wt_ot,
    const float* __restrict__ b_o, u16* __restrict__ F)
{
    __shared__ FSmem u;
    __shared__ float sBias[Hh];
    const int t = threadIdx.x;
    const int row0 = blockIdx.x * 64;
    const int nvalid = min(64, Nn - row0);

    for (int i = t; i < 16 * 512 / 8; i += 256)
        ((uint4*)u.s.Wi)[i] = ((const uint4*)wt_ot)[i];
    {
        uint4 z = make_uint4(0, 0, 0, 0);
        for (int i = t; i < 64 * KI / 8; i += 256) ((uint4*)u.s.A)[i] = z;
    }
    if (t < Hh / 4) ((float4*)sBias)[t] = ((const float4*)b_o)[t];
    __syncthreads();
    for (int i = t; i < nvalid * FFn; i += 256) {
        int r = i / FFn, k = i - r * FFn;
        u.s.A[r * KI + k] = f2bf(features[(size_t)row0 * FFn + i]);
    }
    __syncthreads();

    const int lane = t & 63, wid = t >> 6, l15 = lane & 15, l4 = lane >> 4;
    f32x4 acc[8];
    #pragma unroll
    for (int b = 0; b < 8; ++b) acc[b] = (f32x4){0.f, 0.f, 0.f, 0.f};
    #pragma unroll
    for (int ks = 0; ks < 2; ++ks) {
        s16x8 a = *(const s16x8*)&u.s.A[(wid * 16 + l15) * KI + ks * 32 + l4 * 8];
        #pragma unroll
        for (int c = 0; c < 8; ++c) {
            s16x8 b = ((const s16x8*)u.s.Wi)[(ks * 8 + c) * 64 + lane];
            acc[c] = __builtin_amdgcn_mfma_f32_16x16x32_bf16(a, b, acc[c], 0, 0, 0);
        }
    }
    __syncthreads();

    #pragma unroll
    for (int c = 0; c < 8; ++c)
        #pragma unroll
        for (int j = 0; j < 4; ++j)
            u.acc[wid * 16 + l4 * 4 + j][c * 16 + l15] = acc[c][j];
    __syncthreads();

    for (int i = t; i < 64 * 16; i += 256) {
        int r = i >> 4, seg = i & 15, g = row0 + r;
        if (g < Nn) {
            float4 a0 = *(const float4*)&u.acc[r][seg * 8];
            float4 a1 = *(const float4*)&u.acc[r][seg * 8 + 4];
            const float* bb = &sBias[seg * 8];
            uint4 m;
            m.x = pack2(a0.x + bb[0], a0.y + bb[1]);
            m.y = pack2(a0.z + bb[2], a0.w + bb[3]);
            m.z = pack2(a1.x + bb[4], a1.y + bb[5]);
            m.w = pack2(a1.z + bb[6], a1.w + bb[7]);
            *(uint4*)&F[(size_t)g * Hh + seg * 8] = m;
        }
    }
}

// ---------------------------------------------------------------------------
// k_pool: segment mean over bf16 hidden. One block (128 threads) / molecule.
// ---------------------------------------------------------------------------
__global__ __launch_bounds__(128) void k_pool(
    const u16* __restrict__ hidden, const int* __restrict__ scope,
    float* __restrict__ out)
{
    const int b = blockIdx.x;
    const int t = threadIdx.x;
    const int start = scope[b * 2 + 0];
    const int len   = scope[b * 2 + 1];
    float acc = 0.f;
    for (int i = 0; i < len; ++i)
        acc += bf1(hidden[(size_t)(start + i) * Hh + t]);
    out[(size_t)b * Hh + t] = acc / (float)len;
}

// ---------------------------------------------------------------------------
extern "C" void kernel_launch(void* const* d_in, const int* in_sizes, int n_in,
                              void* d_out, int out_size, void* d_ws, size_t ws_size,
                              hipStream_t stream)
{
    const float* features = (const float*)d_in[0];
    const float* fedges   = (const float*)d_in[1];
    const int*   agraph   = (const int*)d_in[2];
    const int*   egraph   = (const int*)d_in[3];
    const int*   scope    = (const int*)d_in[4];
    const float* W_i      = (const float*)d_in[5];
    const float* W_h      = (const float*)d_in[6];
    const float* W_o      = (const float*)d_in[7];
    const float* b_o      = (const float*)d_in[8];
    float* out = (float*)d_out;

    // Workspace planes (u16, E*128 each): binput | msg0 | msg1 | T | wt_h tail.
    // wt_i parks in msg1 (consumed by k_binput before iter0 writes msg1).
    // msg0 is dead after iter d=4's k_mmul reads it -> wt_ot/wt_ob/F/hidden live there.
    const size_t plane = (size_t)Ee * Hh;
    u16* binput = (u16*)d_ws;
    u16* msg0   = binput + plane;
    u16* msg1   = msg0 + plane;
    u16* Tbuf   = msg1 + plane;
    u16* wt_h   = Tbuf + plane;              // 16384 u16
    u16* wt_i   = msg1;                      // 8192 u16
    u16* wt_ot  = msg0;                      // 8192 u16
    u16* wt_ob  = msg0 + 16 * 512;           // 16384 u16
    u16* Fbuf   = msg0 + 16 * 512 + 32 * 512;        // Nn*128 u16
    u16* hidden = Fbuf + (size_t)Nn * Hh;            // Nn*128 u16

    k_prep1<<<(Hh * Hh + 16 * 512 + 255) / 256, 256, 0, stream>>>(W_h, W_i, wt_h, wt_i);

    k_binput<<<(Ee + 127) / 128, 512, 0, stream>>>(fedges, wt_i, binput, msg0);

    const int mblocks = (Ee + 63) / 64;
    const int gblocks = (Ee * NBn + 255) / 256;
    u16* src = msg0;
    u16* dst = msg1;
    for (int d = 0; d < ITERS; ++d) {
        k_mmul<<<mblocks, 256, 0, stream>>>(src, wt_h, Tbuf, Ee);
        k_gscatter_sig<<<gblocks, 256, 0, stream>>>(Tbuf, egraph, binput, dst, Ee);
        u16* tmp = src; src = dst; dst = tmp;
    }
    // final message in `src` (= msg1); msg0 plane now dead.
    k_prep_o<<<(48 * 512) / 256, 256, 0, stream>>>(W_o, wt_ot, wt_ob);
    k_fgemm<<<(Nn + 63) / 64, 256, 0, stream>>>(features, wt_ot, b_o, Fbuf);
    k_mmul<<<mblocks, 256, 0, stream>>>(src, wt_ob, Tbuf, Ee);
    k_gscatter_sig<<<(Nn * NBn + 255) / 256, 256, 0, stream>>>(Tbuf, agraph, Fbuf, hidden, Nn);

    k_pool<<<Bm, 128, 0, stream>>>(hidden, scope, out);
}